// Round 1
// baseline (309.850 us; speedup 1.0000x reference)
//
#include <hip/hip_runtime.h>
#include <stdint.h>

#define B_ 4
#define S_ 4096
#define D_ 256
#define M_ (B_*S_)  // 16384

typedef __attribute__((ext_vector_type(8))) short bf16x8;
typedef __attribute__((ext_vector_type(4))) float f32x4;
typedef __attribute__((ext_vector_type(4))) unsigned short u16x4;

static __device__ __forceinline__ unsigned short f2bf(float f) {
  union { float f; unsigned u; } v; v.f = f;
  unsigned r = v.u + 0x7fffu + ((v.u >> 16) & 1u);
  return (unsigned short)(r >> 16);
}

// ---------------- f32 -> bf16 convert (with optional scale fold) ----------------
__global__ void cvt_kernel(const float* __restrict__ src, unsigned short* __restrict__ dst,
                           int n4, float scale) {
  int i = blockIdx.x * blockDim.x + threadIdx.x;
  int stride = gridDim.x * blockDim.x;
  for (; i < n4; i += stride) {
    float4 v = reinterpret_cast<const float4*>(src)[i];
    u16x4 o;
    o.x = f2bf(v.x * scale); o.y = f2bf(v.y * scale);
    o.z = f2bf(v.z * scale); o.w = f2bf(v.w * scale);
    reinterpret_cast<u16x4*>(dst)[i] = o;
  }
}

// ---------------- fused QKV projection: y = x @ W^T ----------------
// blockIdx.y: 0=q (plain), 1=k (swizzled rows), 2=v (transposed+swizzled tiles)
__global__ __launch_bounds__(256) void proj_kernel(
    const unsigned short* __restrict__ xb,
    const unsigned short* __restrict__ wq,
    const unsigned short* __restrict__ wk,
    const unsigned short* __restrict__ wv,
    unsigned short* __restrict__ q_ws,
    unsigned short* __restrict__ k_ws,
    unsigned short* __restrict__ vt_ws) {
  const int mat = blockIdx.y;
  const unsigned short* wb = (mat == 0) ? wq : (mat == 1) ? wk : wv;
  const int tid = threadIdx.x;
  const int wave = tid >> 6, lane = tid & 63;
  const int lr = lane & 15, lh = lane >> 4;
  const int row0 = blockIdx.x * 64 + wave * 16;

  // A fragments: x rows (16 rows of this wave), 8 k-chunks of 32
  bf16x8 af[8];
  {
    const unsigned short* xp = xb + (size_t)(row0 + lr) * D_ + lh * 8;
    #pragma unroll
    for (int kc = 0; kc < 8; kc++)
      af[kc] = *reinterpret_cast<const bf16x8*>(xp + kc * 32);
  }

  f32x4 acc[16];
  const f32x4 zero = {0.f, 0.f, 0.f, 0.f};
  #pragma unroll
  for (int n = 0; n < 16; n++) acc[n] = zero;

  #pragma unroll
  for (int kc = 0; kc < 8; kc++) {
    const unsigned short* wp = wb + (size_t)lr * D_ + kc * 32 + lh * 8;
    #pragma unroll
    for (int n = 0; n < 16; n++) {
      bf16x8 bfv = *reinterpret_cast<const bf16x8*>(wp + (size_t)n * 16 * D_);
      acc[n] = __builtin_amdgcn_mfma_f32_16x16x32_bf16(af[kc], bfv, acc[n], 0, 0, 0);
    }
  }

  if (mat == 0) {
    #pragma unroll
    for (int n = 0; n < 16; n++) {
      int col = n * 16 + lr;
      #pragma unroll
      for (int r = 0; r < 4; r++) {
        int row = row0 + lh * 4 + r;
        q_ws[(size_t)row * D_ + col] = f2bf(acc[n][r]);
      }
    }
  } else if (mat == 1) {
    char* kb = reinterpret_cast<char*>(k_ws);
    #pragma unroll
    for (int n = 0; n < 16; n++) {
      int col = n * 16 + lr;
      #pragma unroll
      for (int r = 0; r < 4; r++) {
        int row = row0 + lh * 4 + r;
        size_t byte = (size_t)row * 512 + (size_t)((col * 2) ^ ((row & 7) << 4));
        *reinterpret_cast<unsigned short*>(kb + byte) = f2bf(acc[n][r]);
      }
    }
  } else {
    int row = row0 + lh * 4;           // first of 4 consecutive s rows
    int b = row >> 12, s = row & (S_ - 1);
    int t = s >> 6, sl0 = s & 63;
    char* tbase = reinterpret_cast<char*>(vt_ws) + ((size_t)(b * 64 + t)) * 32768;
    #pragma unroll
    for (int n = 0; n < 16; n++) {
      int e = n * 16 + lr;
      u16x4 o;
      o.x = f2bf(acc[n][0]); o.y = f2bf(acc[n][1]);
      o.z = f2bf(acc[n][2]); o.w = f2bf(acc[n][3]);
      size_t byte = (size_t)((e * 128 + sl0 * 2) ^ ((e & 7) << 4));
      *reinterpret_cast<u16x4*>(tbase + byte) = o;
    }
  }
}

// ---------------- flash attention ----------------
__global__ __launch_bounds__(256) void attn_kernel(
    const unsigned short* __restrict__ q_ws,
    const unsigned short* __restrict__ k_ws,
    const unsigned short* __restrict__ vt_ws,
    float* __restrict__ out) {
  __shared__ char lds_k[2][32768];
  __shared__ char lds_v[2][32768];
  __shared__ char lds_p[4][2048];

  const int bid = blockIdx.x;
  const int b = bid >> 6, qt = bid & 63;
  const int tid = threadIdx.x;
  const int wave = tid >> 6, lane = tid & 63;
  const int lr = lane & 15, lh = lane >> 4;

  const int qrow0 = b * S_ + qt * 64 + wave * 16;

  // Q fragments in registers (scale already folded into Wq)
  bf16x8 qf[8];
  {
    const unsigned short* qp = q_ws + (size_t)(qrow0 + lr) * D_ + lh * 8;
    #pragma unroll
    for (int kc = 0; kc < 8; kc++)
      qf[kc] = *reinterpret_cast<const bf16x8*>(qp + kc * 32);
  }

  f32x4 oacc[16];
  const f32x4 zero = {0.f, 0.f, 0.f, 0.f};
  #pragma unroll
  for (int n = 0; n < 16; n++) oacc[n] = zero;
  float m_r[4], l_r[4];
  #pragma unroll
  for (int r = 0; r < 4; r++) { m_r[r] = -1e30f; l_r[r] = 0.f; }

  const char* kg_base = reinterpret_cast<const char*>(k_ws) + (size_t)b * S_ * 512;
  const char* vg_base = reinterpret_cast<const char*>(vt_ws) + (size_t)b * 64 * 32768;

  auto stage = [&](int t, int buf) {
    const char* kg = kg_base + (size_t)t * 32768;
    const char* vg = vg_base + (size_t)t * 32768;
    char* lk = lds_k[buf];
    char* lv = lds_v[buf];
    #pragma unroll
    for (int i = 0; i < 8; i++) {
      __builtin_amdgcn_global_load_lds(
        (__attribute__((address_space(1))) void*)(void*)(kg + i * 4096 + tid * 16),
        (__attribute__((address_space(3))) void*)(lk + i * 4096 + wave * 1024),
        16, 0, 0);
    }
    #pragma unroll
    for (int i = 0; i < 8; i++) {
      __builtin_amdgcn_global_load_lds(
        (__attribute__((address_space(1))) void*)(void*)(vg + i * 4096 + tid * 16),
        (__attribute__((address_space(3))) void*)(lv + i * 4096 + wave * 1024),
        16, 0, 0);
    }
  };

  stage(0, 0);
  __syncthreads();

  for (int t = 0; t < 64; t++) {
    const int cur = t & 1;
    if (t + 1 < 64) stage(t + 1, cur ^ 1);

    const char* lk = lds_k[cur];
    const char* lv = lds_v[cur];

    // ---- QK^T: 16 q-rows x 64 kv ----
    f32x4 sacc[4];
    #pragma unroll
    for (int n = 0; n < 4; n++) sacc[n] = zero;
    #pragma unroll
    for (int n = 0; n < 4; n++) {
      int krow = n * 16 + lr;
      int sw = (krow & 7) << 4;
      #pragma unroll
      for (int kc = 0; kc < 8; kc++) {
        bf16x8 kf = *reinterpret_cast<const bf16x8*>(lk + krow * 512 + ((kc * 64 + lh * 16) ^ sw));
        sacc[n] = __builtin_amdgcn_mfma_f32_16x16x32_bf16(qf[kc], kf, sacc[n], 0, 0, 0);
      }
    }

    // ---- online softmax (rows owned per-lane: row = lh*4 + r) ----
    float alpha[4], rsum[4];
    #pragma unroll
    for (int r = 0; r < 4; r++) {
      float mx = fmaxf(fmaxf(sacc[0][r], sacc[1][r]), fmaxf(sacc[2][r], sacc[3][r]));
      #pragma unroll
      for (int off = 1; off < 16; off <<= 1)
        mx = fmaxf(mx, __shfl_xor(mx, off));
      float mi = fmaxf(m_r[r], mx);
      alpha[r] = __expf(m_r[r] - mi);
      m_r[r] = mi;
      rsum[r] = 0.f;
    }

    char* pw = lds_p[wave];
    #pragma unroll
    for (int n = 0; n < 4; n++) {
      #pragma unroll
      for (int r = 0; r < 4; r++) {
        float p = __expf(sacc[n][r] - m_r[r]);
        rsum[r] += p;
        int prow = lh * 4 + r;
        int pbyte = prow * 128 + ((((n * 16 + lr) * 2)) ^ ((prow & 7) << 4));
        *reinterpret_cast<unsigned short*>(pw + pbyte) = f2bf(p);
      }
    }
    #pragma unroll
    for (int r = 0; r < 4; r++) {
      float s = rsum[r];
      #pragma unroll
      for (int off = 1; off < 16; off <<= 1)
        s += __shfl_xor(s, off);
      l_r[r] = l_r[r] * alpha[r] + s;
    }

    // rescale existing output accumulator
    #pragma unroll
    for (int n = 0; n < 16; n++) {
      #pragma unroll
      for (int r = 0; r < 4; r++) oacc[n][r] *= alpha[r];
    }

    // ---- PV: A = P [16 x 64], B = V [64 x 16e] from Vt tiles ----
    bf16x8 pa[2];
    #pragma unroll
    for (int ks = 0; ks < 2; ks++) {
      int pbyte = lr * 128 + ((ks * 64 + lh * 16) ^ ((lr & 7) << 4));
      pa[ks] = *reinterpret_cast<const bf16x8*>(pw + pbyte);
    }
    #pragma unroll
    for (int n = 0; n < 16; n++) {
      int vrow = n * 16 + lr;
      int sw = (vrow & 7) << 4;
      #pragma unroll
      for (int ks = 0; ks < 2; ks++) {
        bf16x8 vf = *reinterpret_cast<const bf16x8*>(lv + vrow * 128 + ((ks * 64 + lh * 16) ^ sw));
        oacc[n] = __builtin_amdgcn_mfma_f32_16x16x32_bf16(pa[ks], vf, oacc[n], 0, 0, 0);
      }
    }

    __syncthreads();
  }

  // ---- epilogue: normalize and store f32 ----
  float inv[4];
  #pragma unroll
  for (int r = 0; r < 4; r++) inv[r] = 1.0f / l_r[r];
  #pragma unroll
  for (int n = 0; n < 16; n++) {
    int col = n * 16 + lr;
    #pragma unroll
    for (int r = 0; r < 4; r++) {
      out[(size_t)(qrow0 + lh * 4 + r) * D_ + col] = oacc[n][r] * inv[r];
    }
  }
}

extern "C" void kernel_launch(void* const* d_in, const int* in_sizes, int n_in,
                              void* d_out, int out_size, void* d_ws, size_t ws_size,
                              hipStream_t stream) {
  const float* x  = (const float*)d_in[0];
  const float* Wq = (const float*)d_in[1];
  const float* Wk = (const float*)d_in[2];
  const float* Wv = (const float*)d_in[3];
  float* out = (float*)d_out;

  char* ws = (char*)d_ws;
  unsigned short* xb    = (unsigned short*)(ws);
  unsigned short* wqb   = (unsigned short*)(ws + 8388608);
  unsigned short* wkb   = (unsigned short*)(ws + 8519680);
  unsigned short* wvb   = (unsigned short*)(ws + 8650752);
  unsigned short* q_ws  = (unsigned short*)(ws + 8781824);
  unsigned short* k_ws  = (unsigned short*)(ws + 17170432);
  unsigned short* vt_ws = (unsigned short*)(ws + 25559040);

  // f32 -> bf16 (scale 1/16 folded into Wq)
  cvt_kernel<<<1024, 256, 0, stream>>>(x,  xb,  M_ * D_ / 4, 1.0f);
  cvt_kernel<<<64,   256, 0, stream>>>(Wq, wqb, 65536 / 4, 0.0625f);
  cvt_kernel<<<64,   256, 0, stream>>>(Wk, wkb, 65536 / 4, 1.0f);
  cvt_kernel<<<64,   256, 0, stream>>>(Wv, wvb, 65536 / 4, 1.0f);

  proj_kernel<<<dim3(M_ / 64, 3), 256, 0, stream>>>(xb, wqb, wkb, wvb, q_ws, k_ws, vt_ws);
  attn_kernel<<<256, 256, 0, stream>>>(q_ws, k_ws, vt_ws, out);
}

// Round 3
// 284.659 us; speedup vs baseline: 1.0885x; 1.0885x over previous
//
#include <hip/hip_runtime.h>
#include <stdint.h>

#define B_ 4
#define S_ 4096
#define D_ 256
#define M_ (B_*S_)  // 16384

typedef __attribute__((ext_vector_type(8))) short bf16x8;
typedef __attribute__((ext_vector_type(4))) float f32x4;
typedef __attribute__((ext_vector_type(4))) unsigned short u16x4;

static __device__ __forceinline__ unsigned short f2bf(float f) {
  union { float f; unsigned u; } v; v.f = f;
  unsigned r = v.u + 0x7fffu + ((v.u >> 16) & 1u);
  return (unsigned short)(r >> 16);
}

// ---------------- x: f32 -> bf16 ----------------
__global__ void cvt_kernel(const float* __restrict__ src, unsigned short* __restrict__ dst,
                           int n4) {
  int i = blockIdx.x * blockDim.x + threadIdx.x;
  int stride = gridDim.x * blockDim.x;
  for (; i < n4; i += stride) {
    float4 v = reinterpret_cast<const float4*>(src)[i];
    u16x4 o;
    o.x = f2bf(v.x); o.y = f2bf(v.y);
    o.z = f2bf(v.z); o.w = f2bf(v.w);
    reinterpret_cast<u16x4*>(dst)[i] = o;
  }
}

// ---------------- Wq/Wk/Wv: f32 -> bf16, one launch (scale folded into Wq) ----------------
__global__ void cvt_w_kernel(const float* __restrict__ Wq, const float* __restrict__ Wk,
                             const float* __restrict__ Wv,
                             unsigned short* __restrict__ wqb, unsigned short* __restrict__ wkb,
                             unsigned short* __restrict__ wvb) {
  const int m = blockIdx.y;
  const float* src = (m == 0) ? Wq : (m == 1) ? Wk : Wv;
  unsigned short* dst = (m == 0) ? wqb : (m == 1) ? wkb : wvb;
  const float scale = (m == 0) ? 0.0625f : 1.0f;
  int i = blockIdx.x * 256 + threadIdx.x;  // 64 blocks x 256 thr = 16384 float4 = 65536 elems
  float4 v = reinterpret_cast<const float4*>(src)[i];
  u16x4 o;
  o.x = f2bf(v.x * scale); o.y = f2bf(v.y * scale);
  o.z = f2bf(v.z * scale); o.w = f2bf(v.w * scale);
  reinterpret_cast<u16x4*>(dst)[i] = o;
}

// ---------------- fused QKV projection: y = x @ W^T, W staged in LDS ----------------
// blockIdx.y: 0=q (plain), 1=k (swizzled rows), 2=v (transposed+swizzled tiles)
__global__ __launch_bounds__(256) void proj_kernel(
    const unsigned short* __restrict__ xb,
    const unsigned short* __restrict__ wq,
    const unsigned short* __restrict__ wk,
    const unsigned short* __restrict__ wv,
    unsigned short* __restrict__ q_ws,
    unsigned short* __restrict__ k_ws,
    unsigned short* __restrict__ vt_ws) {
  __shared__ char lw[131072];  // full 256x256 bf16 W, XOR-swizzled rows
  const int mat = blockIdx.y;
  const unsigned short* wb = (mat == 0) ? wq : (mat == 1) ? wk : wv;
  const int tid = threadIdx.x;
  const int wave = tid >> 6, lane = tid & 63;
  const int lr = lane & 15, lh = lane >> 4;

  // stage W -> LDS with st-swizzle (linear LDS dest, pre-swizzled global source)
  {
    const char* wg = reinterpret_cast<const char*>(wb);
    #pragma unroll
    for (int i = 0; i < 32; i++) {
      int off = i * 4096 + tid * 16;
      int r = off >> 9, c = off & 511;
      int src = r * 512 + (c ^ ((r & 7) << 4));
      __builtin_amdgcn_global_load_lds(
        (__attribute__((address_space(1))) void*)(void*)(wg + src),
        (__attribute__((address_space(3))) void*)(lw + off),
        16, 0, 0);
    }
  }
  __syncthreads();

  const f32x4 zero = {0.f, 0.f, 0.f, 0.f};
  #pragma unroll 1
  for (int chunk = 0; chunk < 2; chunk++) {
    const int row0 = (blockIdx.x * 2 + chunk) * 64 + wave * 16;

    bf16x8 af[8];
    {
      const unsigned short* xp = xb + (size_t)(row0 + lr) * D_ + lh * 8;
      #pragma unroll
      for (int kc = 0; kc < 8; kc++)
        af[kc] = *reinterpret_cast<const bf16x8*>(xp + kc * 32);
    }

    f32x4 acc[16];
    #pragma unroll
    for (int n = 0; n < 16; n++) acc[n] = zero;

    #pragma unroll
    for (int kc = 0; kc < 8; kc++) {
      #pragma unroll
      for (int n = 0; n < 16; n++) {
        int wrow = n * 16 + lr;
        bf16x8 bfv = *reinterpret_cast<const bf16x8*>(
            lw + wrow * 512 + ((kc * 64 + lh * 16) ^ ((wrow & 7) << 4)));
        acc[n] = __builtin_amdgcn_mfma_f32_16x16x32_bf16(af[kc], bfv, acc[n], 0, 0, 0);
      }
    }

    if (mat == 0) {
      #pragma unroll
      for (int n = 0; n < 16; n++) {
        int col = n * 16 + lr;
        #pragma unroll
        for (int r = 0; r < 4; r++) {
          int row = row0 + lh * 4 + r;
          q_ws[(size_t)row * D_ + col] = f2bf(acc[n][r]);
        }
      }
    } else if (mat == 1) {
      char* kb = reinterpret_cast<char*>(k_ws);
      #pragma unroll
      for (int n = 0; n < 16; n++) {
        int col = n * 16 + lr;
        #pragma unroll
        for (int r = 0; r < 4; r++) {
          int row = row0 + lh * 4 + r;
          size_t byte = (size_t)row * 512 + (size_t)((col * 2) ^ ((row & 7) << 4));
          *reinterpret_cast<unsigned short*>(kb + byte) = f2bf(acc[n][r]);
        }
      }
    } else {
      int row = row0 + lh * 4;           // first of 4 consecutive s rows
      int b = row >> 12, s = row & (S_ - 1);
      int t = s >> 6, sl0 = s & 63;
      char* tbase = reinterpret_cast<char*>(vt_ws) + ((size_t)(b * 64 + t)) * 32768;
      #pragma unroll
      for (int n = 0; n < 16; n++) {
        int e = n * 16 + lr;
        u16x4 o;
        o.x = f2bf(acc[n][0]); o.y = f2bf(acc[n][1]);
        o.z = f2bf(acc[n][2]); o.w = f2bf(acc[n][3]);
        size_t byte = (size_t)((e * 128 + sl0 * 2) ^ ((e & 7) << 4));
        *reinterpret_cast<u16x4*>(tbase + byte) = o;
      }
    }
  }
}

// ---------------- flash attention ----------------
__global__ __launch_bounds__(256) void attn_kernel(
    const unsigned short* __restrict__ q_ws,
    const unsigned short* __restrict__ k_ws,
    const unsigned short* __restrict__ vt_ws,
    float* __restrict__ out) {
  __shared__ char lds_k[2][32768];
  __shared__ char lds_v[2][32768];
  __shared__ char lds_p[4][2048];

  // XCD-bijective swizzle: 256 blocks, 8 XCDs, bid%8 = XCD -> each XCD gets a
  // contiguous logical range of 32 blocks = ONE batch's K/V (4 MB, L2-resident).
  const int bid0 = blockIdx.x;
  const int bid = (bid0 & 7) * 32 + (bid0 >> 3);
  const int b = bid >> 6, qt = bid & 63;
  const int tid = threadIdx.x;
  const int wave = tid >> 6, lane = tid & 63;
  const int lr = lane & 15, lh = lane >> 4;

  const int qrow0 = b * S_ + qt * 64 + wave * 16;

  // Q fragments in registers (scale already folded into Wq)
  bf16x8 qf[8];
  {
    const unsigned short* qp = q_ws + (size_t)(qrow0 + lr) * D_ + lh * 8;
    #pragma unroll
    for (int kc = 0; kc < 8; kc++)
      qf[kc] = *reinterpret_cast<const bf16x8*>(qp + kc * 32);
  }

  f32x4 oacc[16];
  const f32x4 zero = {0.f, 0.f, 0.f, 0.f};
  #pragma unroll
  for (int n = 0; n < 16; n++) oacc[n] = zero;
  float m_r[4], l_r[4];
  #pragma unroll
  for (int r = 0; r < 4; r++) { m_r[r] = -1e30f; l_r[r] = 0.f; }

  const char* kg_base = reinterpret_cast<const char*>(k_ws) + (size_t)b * S_ * 512;
  const char* vg_base = reinterpret_cast<const char*>(vt_ws) + (size_t)b * 64 * 32768;

  auto stage = [&](int t, int buf) {
    const char* kg = kg_base + (size_t)t * 32768;
    const char* vg = vg_base + (size_t)t * 32768;
    char* lk = lds_k[buf];
    char* lv = lds_v[buf];
    #pragma unroll
    for (int i = 0; i < 8; i++) {
      __builtin_amdgcn_global_load_lds(
        (__attribute__((address_space(1))) void*)(void*)(kg + i * 4096 + tid * 16),
        (__attribute__((address_space(3))) void*)(lk + i * 4096 + wave * 1024),
        16, 0, 0);
    }
    #pragma unroll
    for (int i = 0; i < 8; i++) {
      __builtin_amdgcn_global_load_lds(
        (__attribute__((address_space(1))) void*)(void*)(vg + i * 4096 + tid * 16),
        (__attribute__((address_space(3))) void*)(lv + i * 4096 + wave * 1024),
        16, 0, 0);
    }
  };

  stage(0, 0);
  __syncthreads();

  for (int t = 0; t < 64; t++) {
    const int cur = t & 1;
    if (t + 1 < 64) stage(t + 1, cur ^ 1);

    const char* lk = lds_k[cur];
    const char* lv = lds_v[cur];

    // ---- QK^T: 16 q-rows x 64 kv ----
    f32x4 sacc[4];
    #pragma unroll
    for (int n = 0; n < 4; n++) sacc[n] = zero;
    #pragma unroll
    for (int n = 0; n < 4; n++) {
      int krow = n * 16 + lr;
      int sw = (krow & 7) << 4;
      #pragma unroll
      for (int kc = 0; kc < 8; kc++) {
        bf16x8 kf = *reinterpret_cast<const bf16x8*>(lk + krow * 512 + ((kc * 64 + lh * 16) ^ sw));
        sacc[n] = __builtin_amdgcn_mfma_f32_16x16x32_bf16(qf[kc], kf, sacc[n], 0, 0, 0);
      }
    }

    // ---- online softmax (rows owned per-lane: row = lh*4 + r) ----
    float alpha[4], rsum[4];
    #pragma unroll
    for (int r = 0; r < 4; r++) {
      float mx = fmaxf(fmaxf(sacc[0][r], sacc[1][r]), fmaxf(sacc[2][r], sacc[3][r]));
      #pragma unroll
      for (int off = 1; off < 16; off <<= 1)
        mx = fmaxf(mx, __shfl_xor(mx, off));
      float mi = fmaxf(m_r[r], mx);
      alpha[r] = __expf(m_r[r] - mi);
      m_r[r] = mi;
      rsum[r] = 0.f;
    }

    char* pw = lds_p[wave];
    #pragma unroll
    for (int n = 0; n < 4; n++) {
      #pragma unroll
      for (int r = 0; r < 4; r++) {
        float p = __expf(sacc[n][r] - m_r[r]);
        rsum[r] += p;
        int prow = lh * 4 + r;
        int pbyte = prow * 128 + ((((n * 16 + lr) * 2)) ^ ((prow & 7) << 4));
        *reinterpret_cast<unsigned short*>(pw + pbyte) = f2bf(p);
      }
    }
    #pragma unroll
    for (int r = 0; r < 4; r++) {
      float s = rsum[r];
      #pragma unroll
      for (int off = 1; off < 16; off <<= 1)
        s += __shfl_xor(s, off);
      l_r[r] = l_r[r] * alpha[r] + s;
    }

    // rescale existing output accumulator
    #pragma unroll
    for (int n = 0; n < 16; n++) {
      #pragma unroll
      for (int r = 0; r < 4; r++) oacc[n][r] *= alpha[r];
    }

    // ---- PV: A = P [16 x 64], B = V [64 x 16e] from Vt tiles ----
    bf16x8 pa[2];
    #pragma unroll
    for (int ks = 0; ks < 2; ks++) {
      int pbyte = lr * 128 + ((ks * 64 + lh * 16) ^ ((lr & 7) << 4));
      pa[ks] = *reinterpret_cast<const bf16x8*>(pw + pbyte);
    }
    #pragma unroll
    for (int n = 0; n < 16; n++) {
      int vrow = n * 16 + lr;
      int sw = (vrow & 7) << 4;
      #pragma unroll
      for (int ks = 0; ks < 2; ks++) {
        bf16x8 vf = *reinterpret_cast<const bf16x8*>(lv + vrow * 128 + ((ks * 64 + lh * 16) ^ sw));
        oacc[n] = __builtin_amdgcn_mfma_f32_16x16x32_bf16(pa[ks], vf, oacc[n], 0, 0, 0);
      }
    }

    __syncthreads();
  }

  // ---- epilogue: normalize and store f32 ----
  float inv[4];
  #pragma unroll
  for (int r = 0; r < 4; r++) inv[r] = 1.0f / l_r[r];
  #pragma unroll
  for (int n = 0; n < 16; n++) {
    int col = n * 16 + lr;
    #pragma unroll
    for (int r = 0; r < 4; r++) {
      out[(size_t)(qrow0 + lh * 4 + r) * D_ + col] = oacc[n][r] * inv[r];
    }
  }
}

extern "C" void kernel_launch(void* const* d_in, const int* in_sizes, int n_in,
                              void* d_out, int out_size, void* d_ws, size_t ws_size,
                              hipStream_t stream) {
  const float* x  = (const float*)d_in[0];
  const float* Wq = (const float*)d_in[1];
  const float* Wk = (const float*)d_in[2];
  const float* Wv = (const float*)d_in[3];
  float* out = (float*)d_out;

  char* ws = (char*)d_ws;
  unsigned short* xb    = (unsigned short*)(ws);
  unsigned short* wqb   = (unsigned short*)(ws + 8388608);
  unsigned short* wkb   = (unsigned short*)(ws + 8519680);
  unsigned short* wvb   = (unsigned short*)(ws + 8650752);
  unsigned short* q_ws  = (unsigned short*)(ws + 8781824);
  unsigned short* k_ws  = (unsigned short*)(ws + 17170432);
  unsigned short* vt_ws = (unsigned short*)(ws + 25559040);

  cvt_kernel<<<1024, 256, 0, stream>>>(x, xb, M_ * D_ / 4);
  cvt_w_kernel<<<dim3(64, 3), 256, 0, stream>>>(Wq, Wk, Wv, wqb, wkb, wvb);
  proj_kernel<<<dim3(128, 3), 256, 0, stream>>>(xb, wqb, wkb, wvb, q_ws, k_ws, vt_ws);
  attn_kernel<<<256, 256, 0, stream>>>(q_ws, k_ws, vt_ws, out);
}

// Round 4
// 277.260 us; speedup vs baseline: 1.1175x; 1.0267x over previous
//
#include <hip/hip_runtime.h>
#include <stdint.h>

#define B_ 4
#define S_ 4096
#define D_ 256
#define M_ (B_*S_)  // 16384

typedef __attribute__((ext_vector_type(8))) short bf16x8;
typedef __attribute__((ext_vector_type(4))) float f32x4;
typedef __attribute__((ext_vector_type(4))) unsigned short u16x4;

static __device__ __forceinline__ unsigned short f2bf(float f) {
  union { float f; unsigned u; } v; v.f = f;
  unsigned r = v.u + 0x7fffu + ((v.u >> 16) & 1u);
  return (unsigned short)(r >> 16);
}

// ---------------- x: f32 -> bf16 ----------------
__global__ void cvt_kernel(const float* __restrict__ src, unsigned short* __restrict__ dst,
                           int n4) {
  int i = blockIdx.x * blockDim.x + threadIdx.x;
  int stride = gridDim.x * blockDim.x;
  for (; i < n4; i += stride) {
    float4 v = reinterpret_cast<const float4*>(src)[i];
    u16x4 o;
    o.x = f2bf(v.x); o.y = f2bf(v.y);
    o.z = f2bf(v.z); o.w = f2bf(v.w);
    reinterpret_cast<u16x4*>(dst)[i] = o;
  }
}

// ---------------- Wq/Wk/Wv: f32 -> bf16 (1/16 * log2e folded into Wq) ----------------
__global__ void cvt_w_kernel(const float* __restrict__ Wq, const float* __restrict__ Wk,
                             const float* __restrict__ Wv,
                             unsigned short* __restrict__ wqb, unsigned short* __restrict__ wkb,
                             unsigned short* __restrict__ wvb) {
  const int m = blockIdx.y;
  const float* src = (m == 0) ? Wq : (m == 1) ? Wk : Wv;
  unsigned short* dst = (m == 0) ? wqb : (m == 1) ? wkb : wvb;
  const float scale = (m == 0) ? 0.0625f * 1.44269504f : 1.0f;  // softmax in base-2 domain
  int i = blockIdx.x * 256 + threadIdx.x;
  float4 v = reinterpret_cast<const float4*>(src)[i];
  u16x4 o;
  o.x = f2bf(v.x * scale); o.y = f2bf(v.y * scale);
  o.z = f2bf(v.z * scale); o.w = f2bf(v.w * scale);
  reinterpret_cast<u16x4*>(dst)[i] = o;
}

// ---------------- fused QKV projection: y = x @ W^T, W staged in LDS ----------------
// blockIdx.y: 0=q (plain), 1=k (swizzled rows), 2=v (transposed tiles, attn-LDS-order)
__global__ __launch_bounds__(256) void proj_kernel(
    const unsigned short* __restrict__ xb,
    const unsigned short* __restrict__ wq,
    const unsigned short* __restrict__ wk,
    const unsigned short* __restrict__ wv,
    unsigned short* __restrict__ q_ws,
    unsigned short* __restrict__ k_ws,
    unsigned short* __restrict__ vt_ws) {
  __shared__ char lw[131072];  // full 256x256 bf16 W, XOR-swizzled rows
  const int mat = blockIdx.y;
  const unsigned short* wb = (mat == 0) ? wq : (mat == 1) ? wk : wv;
  const int tid = threadIdx.x;
  const int wave = tid >> 6, lane = tid & 63;
  const int lr = lane & 15, lh = lane >> 4;
  const int row0 = blockIdx.x * 64 + wave * 16;

  // stage W -> LDS with st-swizzle (linear LDS dest, pre-swizzled global source)
  {
    const char* wg = reinterpret_cast<const char*>(wb);
    #pragma unroll
    for (int i = 0; i < 32; i++) {
      int off = i * 4096 + tid * 16;
      int r = off >> 9, c = off & 511;
      int src = r * 512 + (c ^ ((r & 7) << 4));
      __builtin_amdgcn_global_load_lds(
        (__attribute__((address_space(1))) void*)(void*)(wg + src),
        (__attribute__((address_space(3))) void*)(lw + off),
        16, 0, 0);
    }
  }
  __syncthreads();

  const f32x4 zero = {0.f, 0.f, 0.f, 0.f};

  bf16x8 af[8];
  {
    const unsigned short* xp = xb + (size_t)(row0 + lr) * D_ + lh * 8;
    #pragma unroll
    for (int kc = 0; kc < 8; kc++)
      af[kc] = *reinterpret_cast<const bf16x8*>(xp + kc * 32);
  }

  f32x4 acc[16];
  #pragma unroll
  for (int n = 0; n < 16; n++) acc[n] = zero;

  #pragma unroll
  for (int kc = 0; kc < 8; kc++) {
    #pragma unroll
    for (int n = 0; n < 16; n++) {
      int wrow = n * 16 + lr;
      bf16x8 bfv = *reinterpret_cast<const bf16x8*>(
          lw + wrow * 512 + ((kc * 64 + lh * 16) ^ ((wrow & 7) << 4)));
      acc[n] = __builtin_amdgcn_mfma_f32_16x16x32_bf16(af[kc], bfv, acc[n], 0, 0, 0);
    }
  }

  if (mat == 0) {
    #pragma unroll
    for (int n = 0; n < 16; n++) {
      int col = n * 16 + lr;
      #pragma unroll
      for (int r = 0; r < 4; r++) {
        int row = row0 + lh * 4 + r;
        q_ws[(size_t)row * D_ + col] = f2bf(acc[n][r]);
      }
    }
  } else if (mat == 1) {
    char* kb = reinterpret_cast<char*>(k_ws);
    #pragma unroll
    for (int n = 0; n < 16; n++) {
      int col = n * 16 + lr;
      #pragma unroll
      for (int r = 0; r < 4; r++) {
        int row = row0 + lh * 4 + r;
        size_t byte = (size_t)row * 512 + (size_t)((col * 2) ^ ((row & 7) << 4));
        *reinterpret_cast<unsigned short*>(kb + byte) = f2bf(acc[n][r]);
      }
    }
  } else {
    // V^T tiles of 32 kv, laid out exactly as attn's LDS wants them:
    // slot(e-group n, kv-slot g, e-lane lr) at n*1024 + g*256 + lr*16, kv j at byte 2j
    int row = row0 + lh * 4;           // s-row of r=0 (4 consecutive s)
    int b = row >> 12, s = row & (S_ - 1);
    int t2 = s >> 5;                   // 32-kv tile index
    int g = (s & 31) >> 3;             // kv-slot (constant over r: row0 is 16-aligned)
    int pos0 = s & 7;                  // 0 or 4
    char* tbase = reinterpret_cast<char*>(vt_ws) + ((size_t)(b * 128 + t2)) * 16384;
    #pragma unroll
    for (int n = 0; n < 16; n++) {
      u16x4 o;
      o.x = f2bf(acc[n][0]); o.y = f2bf(acc[n][1]);
      o.z = f2bf(acc[n][2]); o.w = f2bf(acc[n][3]);
      *reinterpret_cast<u16x4*>(tbase + n * 1024 + g * 256 + lr * 16 + pos0 * 2) = o;
    }
  }
}

// ---------------- flash attention, split-K (2 halves), KVBLK=32 ----------------
// 512 blocks: xcd = bid&7 -> (batch = xcd>>1, half = xcd&1); idx = bid>>3 = q-tile.
// LDS 68KB -> 2 blocks/CU -> 2 waves/SIMD.
__global__ __launch_bounds__(256) void attn_kernel(
    const unsigned short* __restrict__ q_ws,
    const unsigned short* __restrict__ k_ws,
    const unsigned short* __restrict__ vt_ws,
    float* __restrict__ po, float* __restrict__ pm, float* __restrict__ pl) {
  __shared__ char lds_k[2][16384];
  __shared__ char lds_v[2][16384];
  __shared__ char lds_p[4][1024];

  const int bid0 = blockIdx.x;
  const int xcd = bid0 & 7, qt = bid0 >> 3;
  const int b = xcd >> 1, h = xcd & 1;
  const int tid = threadIdx.x;
  const int wave = tid >> 6, lane = tid & 63;
  const int lr = lane & 15, lh = lane >> 4;

  const int qrow0 = b * S_ + qt * 64 + wave * 16;

  bf16x8 qf[8];
  {
    const unsigned short* qp = q_ws + (size_t)(qrow0 + lr) * D_ + lh * 8;
    #pragma unroll
    for (int kc = 0; kc < 8; kc++)
      qf[kc] = *reinterpret_cast<const bf16x8*>(qp + kc * 32);
  }

  f32x4 oacc[16];
  const f32x4 zero = {0.f, 0.f, 0.f, 0.f};
  #pragma unroll
  for (int n = 0; n < 16; n++) oacc[n] = zero;
  float m_r[4], l_r[4];
  #pragma unroll
  for (int r = 0; r < 4; r++) { m_r[r] = -1e30f; l_r[r] = 0.f; }

  const char* kg_base = reinterpret_cast<const char*>(k_ws) +
                        (size_t)b * S_ * 512 + (size_t)h * 64 * 16384;
  const char* vg_base = reinterpret_cast<const char*>(vt_ws) +
                        ((size_t)(b * 128 + h * 64)) * 16384;

  auto stage = [&](int t, int buf) {
    const char* kg = kg_base + (size_t)t * 16384;
    const char* vg = vg_base + (size_t)t * 16384;
    char* lk = lds_k[buf];
    char* lv = lds_v[buf];
    #pragma unroll
    for (int i = 0; i < 4; i++) {
      __builtin_amdgcn_global_load_lds(
        (__attribute__((address_space(1))) void*)(void*)(kg + i * 4096 + tid * 16),
        (__attribute__((address_space(3))) void*)(lk + i * 4096 + wave * 1024),
        16, 0, 0);
    }
    #pragma unroll
    for (int i = 0; i < 4; i++) {
      __builtin_amdgcn_global_load_lds(
        (__attribute__((address_space(1))) void*)(void*)(vg + i * 4096 + tid * 16),
        (__attribute__((address_space(3))) void*)(lv + i * 4096 + wave * 1024),
        16, 0, 0);
    }
  };

  stage(0, 0);
  __syncthreads();

  for (int t = 0; t < 64; t++) {
    const int cur = t & 1;
    if (t + 1 < 64) stage(t + 1, cur ^ 1);

    const char* lk = lds_k[cur];
    const char* lv = lds_v[cur];

    // ---- QK^T: 16 q-rows x 32 kv ----
    f32x4 sacc[2];
    #pragma unroll
    for (int n = 0; n < 2; n++) sacc[n] = zero;
    #pragma unroll
    for (int n = 0; n < 2; n++) {
      int krow = n * 16 + lr;
      int sw = (krow & 7) << 4;
      #pragma unroll
      for (int kc = 0; kc < 8; kc++) {
        bf16x8 kf = *reinterpret_cast<const bf16x8*>(lk + krow * 512 + ((kc * 64 + lh * 16) ^ sw));
        sacc[n] = __builtin_amdgcn_mfma_f32_16x16x32_bf16(qf[kc], kf, sacc[n], 0, 0, 0);
      }
    }

    // ---- online softmax (base-2 domain; rows owned per-lane: row = lh*4 + r) ----
    float alpha[4], rsum[4];
    #pragma unroll
    for (int r = 0; r < 4; r++) {
      float mx = fmaxf(sacc[0][r], sacc[1][r]);
      #pragma unroll
      for (int off = 1; off < 16; off <<= 1)
        mx = fmaxf(mx, __shfl_xor(mx, off));
      float mi = fmaxf(m_r[r], mx);
      alpha[r] = exp2f(m_r[r] - mi);
      m_r[r] = mi;
      rsum[r] = 0.f;
    }

    char* pw = lds_p[wave];
    #pragma unroll
    for (int n = 0; n < 2; n++) {
      #pragma unroll
      for (int r = 0; r < 4; r++) {
        float p = exp2f(sacc[n][r] - m_r[r]);
        rsum[r] += p;
        int prow = lh * 4 + r;
        int pbyte = prow * 64 + ((n * 32 + lr * 2) ^ (((prow >> 1) & 3) << 4));
        *reinterpret_cast<unsigned short*>(pw + pbyte) = f2bf(p);
      }
    }
    #pragma unroll
    for (int r = 0; r < 4; r++) {
      float s = rsum[r];
      #pragma unroll
      for (int off = 1; off < 16; off <<= 1)
        s += __shfl_xor(s, off);
      l_r[r] = l_r[r] * alpha[r] + s;
    }

    #pragma unroll
    for (int n = 0; n < 16; n++) {
      #pragma unroll
      for (int r = 0; r < 4; r++) oacc[n][r] *= alpha[r];
    }

    // ---- PV: A = P [16 x 32], B = V^T tile (conflict-free linear layout) ----
    bf16x8 pa = *reinterpret_cast<const bf16x8*>(
        pw + lr * 64 + ((lh << 4) ^ (((lr >> 1) & 3) << 4)));
    #pragma unroll
    for (int n = 0; n < 16; n++) {
      bf16x8 vf = *reinterpret_cast<const bf16x8*>(lv + n * 1024 + lane * 16);
      oacc[n] = __builtin_amdgcn_mfma_f32_16x16x32_bf16(pa, vf, oacc[n], 0, 0, 0);
    }

    __syncthreads();
  }

  // ---- epilogue: write unnormalized partials + m,l ----
  #pragma unroll
  for (int n = 0; n < 16; n++) {
    int col = n * 16 + lr;
    #pragma unroll
    for (int r = 0; r < 4; r++) {
      po[((size_t)h * 16384 + qrow0 + lh * 4 + r) * D_ + col] = oacc[n][r];
    }
  }
  if (lr == 0) {
    #pragma unroll
    for (int r = 0; r < 4; r++) {
      int row = qrow0 + lh * 4 + r;
      pm[h * 16384 + row] = m_r[r];
      pl[h * 16384 + row] = l_r[r];
    }
  }
}

// ---------------- merge the two KV-halves ----------------
__global__ __launch_bounds__(256) void merge_kernel(
    const float* __restrict__ po, const float* __restrict__ pm,
    const float* __restrict__ pl, float* __restrict__ out) {
  int idx = blockIdx.x * 256 + threadIdx.x;  // 16384 rows x 64 float4
  int row = idx >> 6, c4 = idx & 63;
  float m0 = pm[row], m1 = pm[16384 + row];
  float l0 = pl[row], l1 = pl[16384 + row];
  float M = fmaxf(m0, m1);
  float a0 = exp2f(m0 - M), a1 = exp2f(m1 - M);
  float inv = 1.0f / (l0 * a0 + l1 * a1);
  float4 o0 = reinterpret_cast<const float4*>(po)[(size_t)row * 64 + c4];
  float4 o1 = reinterpret_cast<const float4*>(po)[(size_t)(16384 + row) * 64 + c4];
  float4 o;
  o.x = (o0.x * a0 + o1.x * a1) * inv;
  o.y = (o0.y * a0 + o1.y * a1) * inv;
  o.z = (o0.z * a0 + o1.z * a1) * inv;
  o.w = (o0.w * a0 + o1.w * a1) * inv;
  reinterpret_cast<float4*>(out)[(size_t)row * 64 + c4] = o;
}

extern "C" void kernel_launch(void* const* d_in, const int* in_sizes, int n_in,
                              void* d_out, int out_size, void* d_ws, size_t ws_size,
                              hipStream_t stream) {
  const float* x  = (const float*)d_in[0];
  const float* Wq = (const float*)d_in[1];
  const float* Wk = (const float*)d_in[2];
  const float* Wv = (const float*)d_in[3];
  float* out = (float*)d_out;

  char* ws = (char*)d_ws;
  unsigned short* xb    = (unsigned short*)(ws);
  unsigned short* wqb   = (unsigned short*)(ws + 8388608);
  unsigned short* wkb   = (unsigned short*)(ws + 8519680);
  unsigned short* wvb   = (unsigned short*)(ws + 8650752);
  unsigned short* q_ws  = (unsigned short*)(ws + 8781824);
  unsigned short* k_ws  = (unsigned short*)(ws + 17170432);
  unsigned short* vt_ws = (unsigned short*)(ws + 25559040);
  float*          po    = (float*)(ws + 33947648);
  float*          pm    = (float*)(ws + 67502080);
  float*          pl    = (float*)(ws + 67633152);

  cvt_kernel<<<1024, 256, 0, stream>>>(x, xb, M_ * D_ / 4);
  cvt_w_kernel<<<dim3(64, 3), 256, 0, stream>>>(Wq, Wk, Wv, wqb, wkb, wvb);
  proj_kernel<<<dim3(256, 3), 256, 0, stream>>>(xb, wqb, wkb, wvb, q_ws, k_ws, vt_ws);
  attn_kernel<<<512, 256, 0, stream>>>(q_ws, k_ws, vt_ws, po, pm, pl);
  merge_kernel<<<4096, 256, 0, stream>>>(po, pm, pl, out);
}

// Round 5
// 206.131 us; speedup vs baseline: 1.5032x; 1.3451x over previous
//
#include <hip/hip_runtime.h>
#include <stdint.h>

#define B_ 4
#define S_ 4096
#define D_ 256
#define M_ (B_*S_)  // 16384

typedef __attribute__((ext_vector_type(8))) short bf16x8;
typedef __attribute__((ext_vector_type(4))) float f32x4;
typedef __attribute__((ext_vector_type(4))) unsigned short u16x4;

static __device__ __forceinline__ unsigned short f2bf(float f) {
  union { float f; unsigned u; } v; v.f = f;
  unsigned r = v.u + 0x7fffu + ((v.u >> 16) & 1u);
  return (unsigned short)(r >> 16);
}

// ---------------- x: f32 -> bf16 ----------------
__global__ void cvt_kernel(const float* __restrict__ src, unsigned short* __restrict__ dst,
                           int n4) {
  int i = blockIdx.x * blockDim.x + threadIdx.x;
  int stride = gridDim.x * blockDim.x;
  for (; i < n4; i += stride) {
    float4 v = reinterpret_cast<const float4*>(src)[i];
    u16x4 o;
    o.x = f2bf(v.x); o.y = f2bf(v.y);
    o.z = f2bf(v.z); o.w = f2bf(v.w);
    reinterpret_cast<u16x4*>(dst)[i] = o;
  }
}

// ---------------- Wq/Wk/Wv: f32 -> bf16 (1/16 * log2e folded into Wq) ----------------
__global__ void cvt_w_kernel(const float* __restrict__ Wq, const float* __restrict__ Wk,
                             const float* __restrict__ Wv,
                             unsigned short* __restrict__ wqb, unsigned short* __restrict__ wkb,
                             unsigned short* __restrict__ wvb) {
  const int m = blockIdx.y;
  const float* src = (m == 0) ? Wq : (m == 1) ? Wk : Wv;
  unsigned short* dst = (m == 0) ? wqb : (m == 1) ? wkb : wvb;
  const float scale = (m == 0) ? 0.0625f * 1.44269504f : 1.0f;  // softmax in base-2 domain
  int i = blockIdx.x * 256 + threadIdx.x;
  float4 v = reinterpret_cast<const float4*>(src)[i];
  u16x4 o;
  o.x = f2bf(v.x * scale); o.y = f2bf(v.y * scale);
  o.z = f2bf(v.z * scale); o.w = f2bf(v.w * scale);
  reinterpret_cast<u16x4*>(dst)[i] = o;
}

// ---------------- fused QKV projection: y = x @ W^T, half-W staged in LDS ----------------
// grid (512, 3): bx>>1 = 64-row tile, bx&1 = 128-col half. blockIdx.y: 0=q, 1=k, 2=v.
// K is written as fragment-linear "A-operand" tiles; V as fragment-linear "B-operand" tiles.
// Per 32-kv tile (16KB): K slot (n,kc,lane)=K[n*16+lr][kc*32+lh*8+j] at (n*8+kc)*1024+lane*16+j*2
//                        V slot: V[k(G,j)][e=ne*16+lre] at ne*1024+G*256+lre*16+j*2,
//                        k(G,j) = (j>>2)*16 + G*4 + (j&3)   (k-order matches P's in-register order)
__global__ __launch_bounds__(256) void proj_kernel(
    const unsigned short* __restrict__ xb,
    const unsigned short* __restrict__ wq,
    const unsigned short* __restrict__ wk,
    const unsigned short* __restrict__ wv,
    unsigned short* __restrict__ q_ws,
    unsigned short* __restrict__ k_ws,
    unsigned short* __restrict__ vt_ws) {
  __shared__ char lw[65536];  // 128 W-rows x 256 d, row-major 512B, XOR-swizzled
  const int mat = blockIdx.y;
  const unsigned short* wb = (mat == 0) ? wq : (mat == 1) ? wk : wv;
  const int bx = blockIdx.x;
  const int rt = bx >> 1, ch = bx & 1;
  const int tid = threadIdx.x;
  const int wave = tid >> 6, lane = tid & 63;
  const int lr = lane & 15, lh = lane >> 4;
  const int row0 = rt * 64 + wave * 16;

  // stage half-W -> LDS (linear dest, pre-swizzled global source)
  {
    const char* wg = reinterpret_cast<const char*>(wb) + ch * 65536;
    #pragma unroll
    for (int i = 0; i < 16; i++) {
      int off = i * 4096 + tid * 16;
      int r = off >> 9, c = off & 511;
      int src = r * 512 + (c ^ ((r & 7) << 4));
      __builtin_amdgcn_global_load_lds(
        (__attribute__((address_space(1))) void*)(void*)(wg + src),
        (__attribute__((address_space(3))) void*)(lw + off),
        16, 0, 0);
    }
  }
  __syncthreads();

  const f32x4 zero = {0.f, 0.f, 0.f, 0.f};

  bf16x8 af[8];
  {
    const unsigned short* xp = xb + (size_t)(row0 + lr) * D_ + lh * 8;
    #pragma unroll
    for (int kc = 0; kc < 8; kc++)
      af[kc] = *reinterpret_cast<const bf16x8*>(xp + kc * 32);
  }

  f32x4 acc[8];
  #pragma unroll
  for (int n = 0; n < 8; n++) acc[n] = zero;

  #pragma unroll
  for (int kc = 0; kc < 8; kc++) {
    #pragma unroll
    for (int n = 0; n < 8; n++) {
      int wrow = n * 16 + lr;  // local row in the staged half
      bf16x8 bfv = *reinterpret_cast<const bf16x8*>(
          lw + wrow * 512 + ((kc * 64 + lh * 16) ^ ((wrow & 7) << 4)));
      acc[n] = __builtin_amdgcn_mfma_f32_16x16x32_bf16(af[kc], bfv, acc[n], 0, 0, 0);
    }
  }

  const int b  = row0 >> 12;
  const int s0 = row0 & 4095;
  const int t2 = s0 >> 5;        // 32-kv tile index (constant per wave)
  const int w1 = wave & 1;       // k-subtile within the 32-kv tile

  if (mat == 0) {
    #pragma unroll
    for (int n = 0; n < 8; n++) {
      int col = ch * 128 + n * 16 + lr;
      #pragma unroll
      for (int r = 0; r < 4; r++) {
        int row = row0 + lh * 4 + r;
        q_ws[(size_t)row * D_ + col] = f2bf(acc[n][r]);
      }
    }
  } else if (mat == 1) {
    char* tb = reinterpret_cast<char*>(k_ws) + ((size_t)(b * 128 + t2)) * 16384;
    #pragma unroll
    for (int n = 0; n < 8; n++) {
      int ng = ch * 8 + n;       // global out-col group = d-chunk of 16
      int base = (w1 * 8 + (ng >> 1)) * 1024 +
                 (((ng & 1) << 1) | (lr >> 3)) * 256 +
                 lh * 64 + (lr & 7) * 2;
      #pragma unroll
      for (int r = 0; r < 4; r++)
        *reinterpret_cast<unsigned short*>(tb + base + r * 16) = f2bf(acc[n][r]);
    }
  } else {
    char* tb = reinterpret_cast<char*>(vt_ws) + ((size_t)(b * 128 + t2)) * 16384;
    #pragma unroll
    for (int n = 0; n < 8; n++) {
      int ng = ch * 8 + n;       // e-group
      u16x4 o;
      o.x = f2bf(acc[n][0]); o.y = f2bf(acc[n][1]);
      o.z = f2bf(acc[n][2]); o.w = f2bf(acc[n][3]);
      *reinterpret_cast<u16x4*>(tb + ng * 1024 + lh * 256 + lr * 16 + w1 * 8) = o;
    }
  }
}

// ---------------- flash attention: swapped QK^T, in-register softmax ----------------
// 256 blocks = 8 XCDs x 32 q-tiles; block = 128 q-rows x 2048 kv (split-K half).
// 4 waves x 32 q-rows (two 16-q groups sharing K/V fragment reads). KVBLK=32.
// LDS 64KB -> 2 blocks/CU. All LDS reads are slot*1024 + lane*16 (conflict-free).
__global__ __launch_bounds__(256, 2) void attn_kernel(
    const unsigned short* __restrict__ q_ws,
    const unsigned short* __restrict__ k_ws,
    const unsigned short* __restrict__ vt_ws,
    float* __restrict__ po, float* __restrict__ pm, float* __restrict__ pl) {
  __shared__ char lds[2][32768];  // per buf: K tile 16KB | V tile 16KB

  const int bid0 = blockIdx.x;
  const int xcd = bid0 & 7, qt = bid0 >> 3;
  const int b = xcd >> 1, h = xcd & 1;
  const int tid = threadIdx.x;
  const int wave = tid >> 6, lane = tid & 63;
  const int lr = lane & 15, lh = lane >> 4;

  const int qrow0 = b * S_ + qt * 128 + wave * 32;

  bf16x8 qfA[8], qfB[8];
  {
    const unsigned short* qpA = q_ws + (size_t)(qrow0 + lr) * D_ + lh * 8;
    const unsigned short* qpB = qpA + 16 * D_;
    #pragma unroll
    for (int kc = 0; kc < 8; kc++) {
      qfA[kc] = *reinterpret_cast<const bf16x8*>(qpA + kc * 32);
      qfB[kc] = *reinterpret_cast<const bf16x8*>(qpB + kc * 32);
    }
  }

  f32x4 oaccA[16], oaccB[16];
  const f32x4 zero = {0.f, 0.f, 0.f, 0.f};
  #pragma unroll
  for (int n = 0; n < 16; n++) { oaccA[n] = zero; oaccB[n] = zero; }
  float mA = -1e30f, mB = -1e30f, lA = 0.f, lB = 0.f;

  const char* kgb = reinterpret_cast<const char*>(k_ws) + ((size_t)(b * 128 + h * 64)) * 16384;
  const char* vgb = reinterpret_cast<const char*>(vt_ws) + ((size_t)(b * 128 + h * 64)) * 16384;

  auto stage = [&](int t, int buf) {
    const char* kg = kgb + (size_t)t * 16384;
    const char* vg = vgb + (size_t)t * 16384;
    char* lk = lds[buf];
    char* lv = lds[buf] + 16384;
    #pragma unroll
    for (int i = 0; i < 4; i++) {
      __builtin_amdgcn_global_load_lds(
        (__attribute__((address_space(1))) void*)(void*)(kg + i * 4096 + tid * 16),
        (__attribute__((address_space(3))) void*)(lk + i * 4096 + tid * 16),
        16, 0, 0);
    }
    #pragma unroll
    for (int i = 0; i < 4; i++) {
      __builtin_amdgcn_global_load_lds(
        (__attribute__((address_space(1))) void*)(void*)(vg + i * 4096 + tid * 16),
        (__attribute__((address_space(3))) void*)(lv + i * 4096 + tid * 16),
        16, 0, 0);
    }
  };

  stage(0, 0);
  __syncthreads();

  for (int t = 0; t < 64; t++) {
    const int cur = t & 1;
    if (t + 1 < 64) stage(t + 1, cur ^ 1);

    const char* lk = lds[cur];
    const char* lv = lds[cur] + 16384;

    // ---- QK^T (swapped): sacc = S^T tile, lane owns q = lr, k = n*16 + lh*4 + r ----
    f32x4 sA0 = zero, sA1 = zero, sB0 = zero, sB1 = zero;
    #pragma unroll
    for (int kc = 0; kc < 8; kc++) {
      bf16x8 kf0 = *reinterpret_cast<const bf16x8*>(lk + kc * 1024 + lane * 16);
      bf16x8 kf1 = *reinterpret_cast<const bf16x8*>(lk + (8 + kc) * 1024 + lane * 16);
      sA0 = __builtin_amdgcn_mfma_f32_16x16x32_bf16(kf0, qfA[kc], sA0, 0, 0, 0);
      sA1 = __builtin_amdgcn_mfma_f32_16x16x32_bf16(kf1, qfA[kc], sA1, 0, 0, 0);
      sB0 = __builtin_amdgcn_mfma_f32_16x16x32_bf16(kf0, qfB[kc], sB0, 0, 0, 0);
      sB1 = __builtin_amdgcn_mfma_f32_16x16x32_bf16(kf1, qfB[kc], sB1, 0, 0, 0);
    }

    // ---- in-register online softmax (base-2), defer-max THR=8 ----
    float pmaxA = fmaxf(fmaxf(fmaxf(sA0[0], sA0[1]), fmaxf(sA0[2], sA0[3])),
                        fmaxf(fmaxf(sA1[0], sA1[1]), fmaxf(sA1[2], sA1[3])));
    float pmaxB = fmaxf(fmaxf(fmaxf(sB0[0], sB0[1]), fmaxf(sB0[2], sB0[3])),
                        fmaxf(fmaxf(sB1[0], sB1[1]), fmaxf(sB1[2], sB1[3])));
    pmaxA = fmaxf(pmaxA, __shfl_xor(pmaxA, 16));
    pmaxA = fmaxf(pmaxA, __shfl_xor(pmaxA, 32));
    pmaxB = fmaxf(pmaxB, __shfl_xor(pmaxB, 16));
    pmaxB = fmaxf(pmaxB, __shfl_xor(pmaxB, 32));

    if (!__all((pmaxA - mA <= 8.f) & (pmaxB - mB <= 8.f))) {
      float miA = fmaxf(mA, pmaxA), miB = fmaxf(mB, pmaxB);
      float aA = exp2f(mA - miA), aB = exp2f(mB - miB);
      mA = miA; mB = miB; lA *= aA; lB *= aB;
      #pragma unroll
      for (int r = 0; r < 4; r++) {
        float avA = __shfl(aA, lh * 4 + r);
        float avB = __shfl(aB, lh * 4 + r);
        #pragma unroll
        for (int n = 0; n < 16; n++) { oaccA[n][r] *= avA; oaccB[n][r] *= avB; }
      }
    }

    bf16x8 paA, paB;
    float sumA = 0.f, sumB = 0.f;
    #pragma unroll
    for (int j = 0; j < 8; j++) {
      float vA = (j < 4) ? sA0[j & 3] : sA1[j & 3];
      float vB = (j < 4) ? sB0[j & 3] : sB1[j & 3];
      float pA = exp2f(vA - mA);
      float pB = exp2f(vB - mB);
      sumA += pA; sumB += pB;
      paA[j] = (short)f2bf(pA);
      paB[j] = (short)f2bf(pB);
    }
    sumA += __shfl_xor(sumA, 16); sumA += __shfl_xor(sumA, 32);
    sumB += __shfl_xor(sumB, 16); sumB += __shfl_xor(sumB, 32);
    lA += sumA; lB += sumB;

    // ---- PV: vf shared across both q-groups ----
    #pragma unroll
    for (int n = 0; n < 16; n++) {
      bf16x8 vf = *reinterpret_cast<const bf16x8*>(lv + n * 1024 + lane * 16);
      oaccA[n] = __builtin_amdgcn_mfma_f32_16x16x32_bf16(paA, vf, oaccA[n], 0, 0, 0);
      oaccB[n] = __builtin_amdgcn_mfma_f32_16x16x32_bf16(paB, vf, oaccB[n], 0, 0, 0);
    }

    __syncthreads();
  }

  // ---- epilogue: unnormalized partials + m,l ----
  const size_t hoff = (size_t)h * 16384;
  #pragma unroll
  for (int n = 0; n < 16; n++) {
    int col = n * 16 + lr;
    #pragma unroll
    for (int r = 0; r < 4; r++) {
      po[(hoff + qrow0 + lh * 4 + r) * D_ + col] = oaccA[n][r];
      po[(hoff + qrow0 + 16 + lh * 4 + r) * D_ + col] = oaccB[n][r];
    }
  }
  if (lh == 0) { pm[hoff + qrow0 + lr] = mA; pl[hoff + qrow0 + lr] = lA; }
  if (lh == 1) { pm[hoff + qrow0 + 16 + lr] = mB; pl[hoff + qrow0 + 16 + lr] = lB; }
}

// ---------------- merge the two KV-halves ----------------
__global__ __launch_bounds__(256) void merge_kernel(
    const float* __restrict__ po, const float* __restrict__ pm,
    const float* __restrict__ pl, float* __restrict__ out) {
  int idx = blockIdx.x * 256 + threadIdx.x;  // 16384 rows x 64 float4
  int row = idx >> 6, c4 = idx & 63;
  float m0 = pm[row], m1 = pm[16384 + row];
  float l0 = pl[row], l1 = pl[16384 + row];
  float M = fmaxf(m0, m1);
  float a0 = exp2f(m0 - M), a1 = exp2f(m1 - M);
  float inv = 1.0f / (l0 * a0 + l1 * a1);
  float4 o0 = reinterpret_cast<const float4*>(po)[(size_t)row * 64 + c4];
  float4 o1 = reinterpret_cast<const float4*>(po)[(size_t)(16384 + row) * 64 + c4];
  float4 o;
  o.x = (o0.x * a0 + o1.x * a1) * inv;
  o.y = (o0.y * a0 + o1.y * a1) * inv;
  o.z = (o0.z * a0 + o1.z * a1) * inv;
  o.w = (o0.w * a0 + o1.w * a1) * inv;
  reinterpret_cast<float4*>(out)[(size_t)row * 64 + c4] = o;
}

extern "C" void kernel_launch(void* const* d_in, const int* in_sizes, int n_in,
                              void* d_out, int out_size, void* d_ws, size_t ws_size,
                              hipStream_t stream) {
  const float* x  = (const float*)d_in[0];
  const float* Wq = (const float*)d_in[1];
  const float* Wk = (const float*)d_in[2];
  const float* Wv = (const float*)d_in[3];
  float* out = (float*)d_out;

  char* ws = (char*)d_ws;
  unsigned short* xb    = (unsigned short*)(ws);
  unsigned short* wqb   = (unsigned short*)(ws + 8388608);
  unsigned short* wkb   = (unsigned short*)(ws + 8519680);
  unsigned short* wvb   = (unsigned short*)(ws + 8650752);
  unsigned short* q_ws  = (unsigned short*)(ws + 8781824);
  unsigned short* k_ws  = (unsigned short*)(ws + 17170432);
  unsigned short* vt_ws = (unsigned short*)(ws + 25559040);
  float*          po    = (float*)(ws + 33947648);
  float*          pm    = (float*)(ws + 67502080);
  float*          pl    = (float*)(ws + 67633152);

  cvt_kernel<<<1024, 256, 0, stream>>>(x, xb, M_ * D_ / 4);
  cvt_w_kernel<<<dim3(64, 3), 256, 0, stream>>>(Wq, Wk, Wv, wqb, wkb, wvb);
  proj_kernel<<<dim3(512, 3), 256, 0, stream>>>(xb, wqb, wkb, wvb, q_ws, k_ws, vt_ws);
  attn_kernel<<<256, 256, 0, stream>>>(q_ws, k_ws, vt_ws, po, pm, pl);
  merge_kernel<<<4096, 256, 0, stream>>>(po, pm, pl, out);
}

// Round 11
// 182.960 us; speedup vs baseline: 1.6935x; 1.1266x over previous
//
#include <hip/hip_runtime.h>
#include <stdint.h>

#define B_ 4
#define S_ 4096
#define D_ 256
#define M_ (B_*S_)  // 16384

typedef __attribute__((ext_vector_type(8))) short bf16x8;
typedef __attribute__((ext_vector_type(8))) unsigned short u16x8;
typedef __attribute__((ext_vector_type(4))) float f32x4;
typedef __attribute__((ext_vector_type(4))) unsigned short u16x4;

static __device__ __forceinline__ unsigned short f2bf(float f) {
  union { float f; unsigned u; } v; v.f = f;
  unsigned r = v.u + 0x7fffu + ((v.u >> 16) & 1u);
  return (unsigned short)(r >> 16);
}
static __device__ __forceinline__ float bf2f(unsigned short h) {
  union { unsigned u; float f; } v; v.u = ((unsigned)h) << 16;
  return v.f;
}

// ---------------- x: f32 -> bf16 ----------------
__global__ void cvt_kernel(const float* __restrict__ src, unsigned short* __restrict__ dst,
                           int n4) {
  int i = blockIdx.x * blockDim.x + threadIdx.x;
  int stride = gridDim.x * blockDim.x;
  for (; i < n4; i += stride) {
    float4 v = reinterpret_cast<const float4*>(src)[i];
    u16x4 o;
    o.x = f2bf(v.x); o.y = f2bf(v.y);
    o.z = f2bf(v.z); o.w = f2bf(v.w);
    reinterpret_cast<u16x4*>(dst)[i] = o;
  }
}

// ---------------- Wq/Wk/Wv -> bf16 in FRAGMENT-LINEAR B-operand layout ----------------
// frag(kc,n) at ushort offset (kc*16+n)*512 + lane*8, holding W[n*16+lr][kc*32+lh*8 .. +7]
__global__ void cvt_w_kernel(const float* __restrict__ Wq, const float* __restrict__ Wk,
                             const float* __restrict__ Wv,
                             unsigned short* __restrict__ wqb, unsigned short* __restrict__ wkb,
                             unsigned short* __restrict__ wvb) {
  const int m = blockIdx.y;
  const float* src = (m == 0) ? Wq : (m == 1) ? Wk : Wv;
  unsigned short* dst = (m == 0) ? wqb : (m == 1) ? wkb : wvb;
  const float scale = (m == 0) ? 0.0625f * 1.44269504f : 1.0f;  // 1/sqrt(256) * log2(e)
  int i = blockIdx.x * 256 + threadIdx.x;  // 8192 chunks of 8 elems
  int frag = i >> 6, lane = i & 63;
  int kc = frag >> 4, n = frag & 15;
  int lr = lane & 15, lh = lane >> 4;
  const float* sp = src + (size_t)(n * 16 + lr) * D_ + kc * 32 + lh * 8;
  float4 a = reinterpret_cast<const float4*>(sp)[0];
  float4 b = reinterpret_cast<const float4*>(sp)[1];
  u16x8 o;
  o[0] = f2bf(a.x * scale); o[1] = f2bf(a.y * scale);
  o[2] = f2bf(a.z * scale); o[3] = f2bf(a.w * scale);
  o[4] = f2bf(b.x * scale); o[5] = f2bf(b.y * scale);
  o[6] = f2bf(b.z * scale); o[7] = f2bf(b.w * scale);
  *reinterpret_cast<u16x8*>(dst + (size_t)frag * 512 + lane * 8) = o;
}

// ---------------- fused QKV projection: y = x @ W^T, W streamed from L2 ----------------
// grid (256, 3): bx = 64-row tile. blockIdx.y: 0=q, 1=k, 2=v. No LDS.
__global__ __launch_bounds__(256, 3) void proj_kernel(
    const unsigned short* __restrict__ xb,
    const unsigned short* __restrict__ wq,
    const unsigned short* __restrict__ wk,
    const unsigned short* __restrict__ wv,
    unsigned short* __restrict__ q_ws,
    unsigned short* __restrict__ k_ws,
    unsigned short* __restrict__ vt_ws) {
  const int mat = blockIdx.y;
  const unsigned short* wb = (mat == 0) ? wq : (mat == 1) ? wk : wv;
  const int tid = threadIdx.x;
  const int wave = tid >> 6, lane = tid & 63;
  const int lr = lane & 15, lh = lane >> 4;
  const int row0 = blockIdx.x * 64 + wave * 16;

  const f32x4 zero = {0.f, 0.f, 0.f, 0.f};

  bf16x8 af[8];
  {
    const unsigned short* xp = xb + (size_t)(row0 + lr) * D_ + lh * 8;
    #pragma unroll
    for (int kc = 0; kc < 8; kc++)
      af[kc] = *reinterpret_cast<const bf16x8*>(xp + kc * 32);
  }

  f32x4 acc[16];
  #pragma unroll
  for (int n = 0; n < 16; n++) acc[n] = zero;

  #pragma unroll
  for (int kc = 0; kc < 8; kc++) {
    #pragma unroll
    for (int n = 0; n < 16; n++) {
      bf16x8 wf = *reinterpret_cast<const bf16x8*>(wb + (size_t)(kc * 16 + n) * 512 + lane * 8);
      acc[n] = __builtin_amdgcn_mfma_f32_16x16x32_bf16(af[kc], wf, acc[n], 0, 0, 0);
    }
  }

  const int b  = row0 >> 12;
  const int s0 = row0 & 4095;
  const int t2 = s0 >> 5;        // 32-kv tile index (constant per wave)
  const int w1 = wave & 1;       // k-subtile within the 32-kv tile

  if (mat == 0) {
    #pragma unroll
    for (int n = 0; n < 16; n++) {
      int col = n * 16 + lr;
      #pragma unroll
      for (int r = 0; r < 4; r++) {
        int row = row0 + lh * 4 + r;
        q_ws[(size_t)row * D_ + col] = f2bf(acc[n][r]);
      }
    }
  } else if (mat == 1) {
    // K as fragment-linear A-operand tiles (16KB per 32 kv)
    char* tb = reinterpret_cast<char*>(k_ws) + ((size_t)(b * 128 + t2)) * 16384;
    #pragma unroll
    for (int n = 0; n < 16; n++) {
      int base = (w1 * 8 + (n >> 1)) * 1024 +
                 (((n & 1) << 1) | (lr >> 3)) * 256 +
                 lh * 64 + (lr & 7) * 2;
      #pragma unroll
      for (int r = 0; r < 4; r++)
        *reinterpret_cast<unsigned short*>(tb + base + r * 16) = f2bf(acc[n][r]);
    }
  } else {
    // V as fragment-linear B-operand tiles
    char* tb = reinterpret_cast<char*>(vt_ws) + ((size_t)(b * 128 + t2)) * 16384;
    #pragma unroll
    for (int n = 0; n < 16; n++) {
      u16x4 o;
      o.x = f2bf(acc[n][0]); o.y = f2bf(acc[n][1]);
      o.z = f2bf(acc[n][2]); o.w = f2bf(acc[n][3]);
      *reinterpret_cast<u16x4*>(tb + n * 1024 + lh * 256 + lr * 16 + w1 * 8) = o;
    }
  }
}

// ---------------- flash attention: swapped QK^T, split-K=4, KVBLK=32 ----------------
// 512 blocks = 8 XCDs x 64; xcd -> (batch, split-pair); block = 128 q x 1024 kv.
// 4 waves x 32 q. LDS 64KB -> 2 blocks/CU. All LDS reads slot*1024+lane*16 (conflict-free).
__global__ __launch_bounds__(256, 2) void attn_kernel(
    const unsigned short* __restrict__ q_ws,
    const unsigned short* __restrict__ k_ws,
    const unsigned short* __restrict__ vt_ws,
    unsigned short* __restrict__ po, float* __restrict__ pm, float* __restrict__ pl) {
  __shared__ char lds[2][32768];  // per buf: K tile 16KB | V tile 16KB

  const int bid0 = blockIdx.x;
  const int xcd = bid0 & 7, idx = bid0 >> 3;       // idx in [0,64)
  const int b = xcd >> 1;
  const int h = (xcd & 1) * 2 + (idx >> 5);        // split in [0,4)
  const int qt = idx & 31;
  const int tid = threadIdx.x;
  const int wave = tid >> 6, lane = tid & 63;
  const int lr = lane & 15, lh = lane >> 4;

  const int qrow0 = b * S_ + qt * 128 + wave * 32;

  bf16x8 qfA[8], qfB[8];
  {
    const unsigned short* qpA = q_ws + (size_t)(qrow0 + lr) * D_ + lh * 8;
    const unsigned short* qpB = qpA + 16 * D_;
    #pragma unroll
    for (int kc = 0; kc < 8; kc++) {
      qfA[kc] = *reinterpret_cast<const bf16x8*>(qpA + kc * 32);
      qfB[kc] = *reinterpret_cast<const bf16x8*>(qpB + kc * 32);
    }
  }

  f32x4 oaccA[16], oaccB[16];
  const f32x4 zero = {0.f, 0.f, 0.f, 0.f};
  #pragma unroll
  for (int n = 0; n < 16; n++) { oaccA[n] = zero; oaccB[n] = zero; }
  float mA = -1e30f, mB = -1e30f, lA = 0.f, lB = 0.f;

  const char* kgb = reinterpret_cast<const char*>(k_ws) + ((size_t)(b * 128 + h * 32)) * 16384;
  const char* vgb = reinterpret_cast<const char*>(vt_ws) + ((size_t)(b * 128 + h * 32)) * 16384;

  auto stage = [&](int t, int buf) {
    const char* kg = kgb + (size_t)t * 16384;
    const char* vg = vgb + (size_t)t * 16384;
    char* lk = lds[buf];
    char* lv = lds[buf] + 16384;
    #pragma unroll
    for (int i = 0; i < 4; i++) {
      __builtin_amdgcn_global_load_lds(
        (__attribute__((address_space(1))) void*)(void*)(kg + i * 4096 + tid * 16),
        (__attribute__((address_space(3))) void*)(lk + i * 4096 + tid * 16),
        16, 0, 0);
    }
    #pragma unroll
    for (int i = 0; i < 4; i++) {
      __builtin_amdgcn_global_load_lds(
        (__attribute__((address_space(1))) void*)(void*)(vg + i * 4096 + tid * 16),
        (__attribute__((address_space(3))) void*)(lv + i * 4096 + tid * 16),
        16, 0, 0);
    }
  };

  stage(0, 0);
  __syncthreads();

  for (int t = 0; t < 32; t++) {
    const int cur = t & 1;
    if (t + 1 < 32) stage(t + 1, cur ^ 1);

    const char* lk = lds[cur];
    const char* lv = lds[cur] + 16384;

    // ---- QK^T (swapped): lane owns q = lr, k = n*16 + lh*4 + r ----
    f32x4 sA0 = zero, sA1 = zero, sB0 = zero, sB1 = zero;
    __builtin_amdgcn_s_setprio(1);
    #pragma unroll
    for (int kc = 0; kc < 8; kc++) {
      bf16x8 kf0 = *reinterpret_cast<const bf16x8*>(lk + kc * 1024 + lane * 16);
      bf16x8 kf1 = *reinterpret_cast<const bf16x8*>(lk + (8 + kc) * 1024 + lane * 16);
      sA0 = __builtin_amdgcn_mfma_f32_16x16x32_bf16(kf0, qfA[kc], sA0, 0, 0, 0);
      sA1 = __builtin_amdgcn_mfma_f32_16x16x32_bf16(kf1, qfA[kc], sA1, 0, 0, 0);
      sB0 = __builtin_amdgcn_mfma_f32_16x16x32_bf16(kf0, qfB[kc], sB0, 0, 0, 0);
      sB1 = __builtin_amdgcn_mfma_f32_16x16x32_bf16(kf1, qfB[kc], sB1, 0, 0, 0);
    }
    __builtin_amdgcn_s_setprio(0);

    // ---- in-register online softmax (base-2), defer-max THR=8 ----
    float pmaxA = fmaxf(fmaxf(fmaxf(sA0[0], sA0[1]), fmaxf(sA0[2], sA0[3])),
                        fmaxf(fmaxf(sA1[0], sA1[1]), fmaxf(sA1[2], sA1[3])));
    float pmaxB = fmaxf(fmaxf(fmaxf(sB0[0], sB0[1]), fmaxf(sB0[2], sB0[3])),
                        fmaxf(fmaxf(sB1[0], sB1[1]), fmaxf(sB1[2], sB1[3])));
    pmaxA = fmaxf(pmaxA, __shfl_xor(pmaxA, 16));
    pmaxA = fmaxf(pmaxA, __shfl_xor(pmaxA, 32));
    pmaxB = fmaxf(pmaxB, __shfl_xor(pmaxB, 16));
    pmaxB = fmaxf(pmaxB, __shfl_xor(pmaxB, 32));

    if (!__all((pmaxA - mA <= 8.f) & (pmaxB - mB <= 8.f))) {
      float miA = fmaxf(mA, pmaxA), miB = fmaxf(mB, pmaxB);
      float aA = exp2f(mA - miA), aB = exp2f(mB - miB);
      mA = miA; mB = miB; lA *= aA; lB *= aB;
      #pragma unroll
      for (int r = 0; r < 4; r++) {
        float avA = __shfl(aA, lh * 4 + r);
        float avB = __shfl(aB, lh * 4 + r);
        #pragma unroll
        for (int n = 0; n < 16; n++) { oaccA[n][r] *= avA; oaccB[n][r] *= avB; }
      }
    }

    bf16x8 paA, paB;
    float sumA = 0.f, sumB = 0.f;
    #pragma unroll
    for (int j = 0; j < 8; j++) {
      float vA = (j < 4) ? sA0[j & 3] : sA1[j & 3];
      float vB = (j < 4) ? sB0[j & 3] : sB1[j & 3];
      float pA = exp2f(vA - mA);
      float pB = exp2f(vB - mB);
      sumA += pA; sumB += pB;
      paA[j] = (short)f2bf(pA);
      paB[j] = (short)f2bf(pB);
    }
    sumA += __shfl_xor(sumA, 16); sumA += __shfl_xor(sumA, 32);
    sumB += __shfl_xor(sumB, 16); sumB += __shfl_xor(sumB, 32);
    lA += sumA; lB += sumB;

    // ---- PV: vf shared across both q-groups ----
    __builtin_amdgcn_s_setprio(1);
    #pragma unroll
    for (int n = 0; n < 16; n++) {
      bf16x8 vf = *reinterpret_cast<const bf16x8*>(lv + n * 1024 + lane * 16);
      oaccA[n] = __builtin_amdgcn_mfma_f32_16x16x32_bf16(paA, vf, oaccA[n], 0, 0, 0);
      oaccB[n] = __builtin_amdgcn_mfma_f32_16x16x32_bf16(paB, vf, oaccB[n], 0, 0, 0);
    }
    __builtin_amdgcn_s_setprio(0);

    __syncthreads();
  }

  // ---- epilogue: transpose via (now free) LDS, then coalesced bf16 stores ----
  char* pwv = &lds[0][0] + wave * 16384;  // 32 rows x 512B per wave
  #pragma unroll
  for (int n = 0; n < 16; n++) {
    int colb = (n * 16 + lr) * 2;
    #pragma unroll
    for (int r = 0; r < 4; r++) {
      *reinterpret_cast<unsigned short*>(pwv + (lh * 4 + r) * 512 + colb) = f2bf(oaccA[n][r]);
      *reinterpret_cast<unsigned short*>(pwv + (16 + lh * 4 + r) * 512 + colb) = f2bf(oaccB[n][r]);
    }
  }
  __syncthreads();
  {
    unsigned short* pob = po + ((size_t)h * 16384 + qrow0) * D_;
    #pragma unroll
    for (int i = 0; i < 16; i++) {
      int off = i * 1024 + lane * 16;
      bf16x8 v = *reinterpret_cast<const bf16x8*>(pwv + off);
      int row = off >> 9, colb = off & 511;
      *reinterpret_cast<bf16x8*>(reinterpret_cast<char*>(pob) + row * 512 + colb) = v;
    }
  }
  if (lh == 0) { pm[(size_t)h * 16384 + qrow0 + lr] = mA; pl[(size_t)h * 16384 + qrow0 + lr] = lA; }
  if (lh == 1) { pm[(size_t)h * 16384 + qrow0 + 16 + lr] = mB; pl[(size_t)h * 16384 + qrow0 + 16 + lr] = lB; }
}

// ---------------- merge the four KV-splits ----------------
__global__ __launch_bounds__(256) void merge_kernel(
    const unsigned short* __restrict__ po, const float* __restrict__ pm,
    const float* __restrict__ pl, float* __restrict__ out) {
  int idx = blockIdx.x * 256 + threadIdx.x;  // 16384 rows x 32 chunks of 8
  int row = idx >> 5, c8 = idx & 31;
  float m0 = pm[row], m1 = pm[16384 + row], m2 = pm[32768 + row], m3 = pm[49152 + row];
  float l0 = pl[row], l1 = pl[16384 + row], l2 = pl[32768 + row], l3 = pl[49152 + row];
  float M = fmaxf(fmaxf(m0, m1), fmaxf(m2, m3));
  float a0 = exp2f(m0 - M), a1 = exp2f(m1 - M), a2 = exp2f(m2 - M), a3 = exp2f(m3 - M);
  float inv = 1.0f / (l0 * a0 + l1 * a1 + l2 * a2 + l3 * a3);
  float acc[8];
  #pragma unroll
  for (int j = 0; j < 8; j++) acc[j] = 0.f;
  const float aw[4] = {a0, a1, a2, a3};
  #pragma unroll
  for (int hh = 0; hh < 4; hh++) {
    u16x8 v = *reinterpret_cast<const u16x8*>(po + ((size_t)hh * 16384 + row) * D_ + c8 * 8);
    #pragma unroll
    for (int j = 0; j < 8; j++) acc[j] += aw[hh] * bf2f(v[j]);
  }
  float4 o0, o1;
  o0.x = acc[0] * inv; o0.y = acc[1] * inv; o0.z = acc[2] * inv; o0.w = acc[3] * inv;
  o1.x = acc[4] * inv; o1.y = acc[5] * inv; o1.z = acc[6] * inv; o1.w = acc[7] * inv;
  float4* op = reinterpret_cast<float4*>(out + (size_t)row * D_ + c8 * 8);
  op[0] = o0; op[1] = o1;
}

extern "C" void kernel_launch(void* const* d_in, const int* in_sizes, int n_in,
                              void* d_out, int out_size, void* d_ws, size_t ws_size,
                              hipStream_t stream) {
  const float* x  = (const float*)d_in[0];
  const float* Wq = (const float*)d_in[1];
  const float* Wk = (const float*)d_in[2];
  const float* Wv = (const float*)d_in[3];
  float* out = (float*)d_out;

  char* ws = (char*)d_ws;
  unsigned short* xb    = (unsigned short*)(ws);
  unsigned short* wqb   = (unsigned short*)(ws + 8388608);
  unsigned short* wkb   = (unsigned short*)(ws + 8519680);
  unsigned short* wvb   = (unsigned short*)(ws + 8650752);
  unsigned short* q_ws  = (unsigned short*)(ws + 8781824);
  unsigned short* k_ws  = (unsigned short*)(ws + 17170432);
  unsigned short* vt_ws = (unsigned short*)(ws + 25559040);
  unsigned short* po    = (unsigned short*)(ws + 33947648);  // 33.5MB bf16 [4][16384][256]
  float*          pm    = (float*)(ws + 67502080);
  float*          pl    = (float*)(ws + 67764224);

  cvt_kernel<<<1024, 256, 0, stream>>>(x, xb, M_ * D_ / 4);
  cvt_w_kernel<<<dim3(32, 3), 256, 0, stream>>>(Wq, Wk, Wv, wqb, wkb, wvb);
  proj_kernel<<<dim3(256, 3), 256, 0, stream>>>(xb, wqb, wkb, wvb, q_ws, k_ws, vt_ws);
  attn_kernel<<<512, 256, 0, stream>>>(q_ws, k_ws, vt_ws, po, pm, pl);
  merge_kernel<<<2048, 256, 0, stream>>>(po, pm, pl, out);
}